// Round 1
// baseline (2896.865 us; speedup 1.0000x reference)
//
#include <hip/hip_runtime.h>

// ---------------------------------------------------------------------------
// VariationalGCNEncoder: mu/logstd = GCNConv(relu(GCNConv(x)))
// N=100000 nodes, E=1600000 edges, IN=256, HID=128, OUT=64
//
// Pipeline (all f32 this round):
//  1. deg[i] = 1 + count(dst==i);  dinv = rsqrt(deg)
//  2. h1 = x @ W1                       [N,128]   (GEMM, 8x8 register tile)
//  3. agg1 = A_norm * h1  (self-loop init + edge atomics)
//  4. h = relu(agg1 + b1)
//  5. agg2 = A_norm * h
//  6. mu = agg2 @ W_mu + b_mu ; ls = agg2 @ W_ls + b_ls  (fused GEMM)
// ---------------------------------------------------------------------------

__global__ __launch_bounds__(256) void k_init_deg(float* __restrict__ deg, int N) {
    int i = blockIdx.x * 256 + threadIdx.x;
    if (i < N) deg[i] = 1.0f;  // self-loop
}

__global__ __launch_bounds__(256) void k_count_deg(const int* __restrict__ dst,
                                                   float* __restrict__ deg, int E) {
    int e = blockIdx.x * 256 + threadIdx.x;
    if (e < E) atomicAdd(&deg[dst[e]], 1.0f);
}

__global__ __launch_bounds__(256) void k_rsqrt(float* __restrict__ deg, int N) {
    int i = blockIdx.x * 256 + threadIdx.x;
    if (i < N) deg[i] = rsqrtf(deg[i]);
}

// Hout[i,:] = Hin[i,:] * dinv[i]^2   (self-loop contribution, also initializes Hout)
__global__ __launch_bounds__(256) void k_selfloop(const float* __restrict__ Hin,
                                                  const float* __restrict__ dinv,
                                                  float* __restrict__ Hout, int N) {
    int idx = blockIdx.x * 256 + threadIdx.x;   // float4 index, N*32 total
    if (idx >= N * 32) return;
    int node = idx >> 5;
    float di = dinv[node];
    float w = di * di;
    float4 v = ((const float4*)Hin)[idx];
    v.x *= w; v.y *= w; v.z *= w; v.w *= w;
    ((float4*)Hout)[idx] = v;
}

// one wave per edge; lane handles 2 channels (128 ch total)
__global__ __launch_bounds__(256) void k_agg_edges(const int* __restrict__ src,
                                                   const int* __restrict__ dst,
                                                   const float* __restrict__ dinv,
                                                   const float* __restrict__ Hin,
                                                   float* __restrict__ Hout, int E) {
    int gw = (blockIdx.x * 256 + threadIdx.x) >> 6;  // global wave id = edge id
    int lane = threadIdx.x & 63;
    if (gw >= E) return;
    int s = src[gw], d = dst[gw];
    float w = dinv[s] * dinv[d];
    float2 v = ((const float2*)(Hin + (size_t)s * 128))[lane];
    float* o = Hout + (size_t)d * 128 + lane * 2;
    atomicAdd(o, v.x * w);
    atomicAdd(o + 1, v.y * w);
}

__global__ __launch_bounds__(256) void k_relu_bias(float* __restrict__ H,
                                                   const float* __restrict__ b, int N) {
    int idx = blockIdx.x * 256 + threadIdx.x;   // float4 index, N*32 total
    if (idx >= N * 32) return;
    float4 bb = ((const float4*)b)[idx & 31];
    float4 v = ((float4*)H)[idx];
    v.x = fmaxf(v.x + bb.x, 0.f);
    v.y = fmaxf(v.y + bb.y, 0.f);
    v.z = fmaxf(v.z + bb.z, 0.f);
    v.w = fmaxf(v.w + bb.w, 0.f);
    ((float4*)H)[idx] = v;
}

// ---------------------------------------------------------------------------
// Tiled f32 GEMM: C[M,128] = A[M,K] @ B[K,128]; 128x128 tile, 8x8 per thread.
// EPI==0: plain store to C0 (stride 128).
// EPI==1: B = [W_mu | W_ls] (each [K,64]); cols 0..63 -> C0+bias0 (stride 64),
//         cols 64..127 -> C1+bias1 (stride 64).
// ---------------------------------------------------------------------------
template <int K, int EPI>
__global__ __launch_bounds__(256) void k_gemm(const float* __restrict__ A,
                                              const float* __restrict__ B0,
                                              const float* __restrict__ B1,
                                              float* __restrict__ C0,
                                              float* __restrict__ C1,
                                              const float* __restrict__ bias0,
                                              const float* __restrict__ bias1, int M) {
    __shared__ float As[32][132];  // transposed A tile [k][m], +4 pad (16B-aligned rows)
    __shared__ float Bs[32][128];  // B tile [k][n]
    const int t = threadIdx.x;
    const int tx = t & 15, ty = t >> 4;
    const int rowBase = ty * 8, colBase = tx * 8;
    const int blockRow = blockIdx.x * 128;

    float acc[8][8];
#pragma unroll
    for (int i = 0; i < 8; i++)
#pragma unroll
        for (int j = 0; j < 8; j++) acc[i][j] = 0.f;

    for (int k0 = 0; k0 < K; k0 += 32) {
        // --- stage A tile (128 rows x 32 k), transposed into As[k][m]
#pragma unroll
        for (int i = 0; i < 4; ++i) {
            int f = i * 256 + t;        // [0,1024) float4 slots
            int m = f >> 3;             // 0..127
            int kq = (f & 7) * 4;       // 0,4,..,28
            int gr = blockRow + m;
            float4 v = make_float4(0.f, 0.f, 0.f, 0.f);
            if (gr < M) v = *(const float4*)(A + (size_t)gr * K + k0 + kq);
            As[kq + 0][m] = v.x;
            As[kq + 1][m] = v.y;
            As[kq + 2][m] = v.z;
            As[kq + 3][m] = v.w;
        }
        // --- stage B tile (32 k x 128 n)
#pragma unroll
        for (int i = 0; i < 4; ++i) {
            int f = i * 256 + t;
            int kk = f >> 5;            // 0..31
            int n4 = (f & 31) * 4;      // 0..124
            float4 v;
            if (EPI == 0) {
                v = *(const float4*)(B0 + (size_t)(k0 + kk) * 128 + n4);
            } else {
                const float* Bp = (n4 < 64) ? (B0 + (size_t)(k0 + kk) * 64 + n4)
                                            : (B1 + (size_t)(k0 + kk) * 64 + (n4 - 64));
                v = *(const float4*)Bp;
            }
            *(float4*)&Bs[kk][n4] = v;
        }
        __syncthreads();
#pragma unroll
        for (int k = 0; k < 32; ++k) {
            float a[8], b[8];
            *(float4*)&a[0] = *(const float4*)&As[k][rowBase];
            *(float4*)&a[4] = *(const float4*)&As[k][rowBase + 4];
            *(float4*)&b[0] = *(const float4*)&Bs[k][colBase];
            *(float4*)&b[4] = *(const float4*)&Bs[k][colBase + 4];
#pragma unroll
            for (int i = 0; i < 8; i++)
#pragma unroll
                for (int j = 0; j < 8; j++) acc[i][j] = fmaf(a[i], b[j], acc[i][j]);
        }
        __syncthreads();
    }

    if (EPI == 0) {
#pragma unroll
        for (int i = 0; i < 8; i++) {
            int m = blockRow + rowBase + i;
            if (m < M) {
                *(float4*)(C0 + (size_t)m * 128 + colBase) = *(float4*)&acc[i][0];
                *(float4*)(C0 + (size_t)m * 128 + colBase + 4) = *(float4*)&acc[i][4];
            }
        }
    } else {
        const bool isMu = (colBase < 64);
        const float* bias = isMu ? bias0 : bias1;
        float* C = isMu ? C0 : C1;
        const int cb = isMu ? colBase : colBase - 64;
        float bb[8];
#pragma unroll
        for (int j = 0; j < 8; j++) bb[j] = bias[cb + j];
#pragma unroll
        for (int i = 0; i < 8; i++) {
            int m = blockRow + rowBase + i;
            if (m < M) {
                float4 v0, v1;
                v0.x = acc[i][0] + bb[0]; v0.y = acc[i][1] + bb[1];
                v0.z = acc[i][2] + bb[2]; v0.w = acc[i][3] + bb[3];
                v1.x = acc[i][4] + bb[4]; v1.y = acc[i][5] + bb[5];
                v1.z = acc[i][6] + bb[6]; v1.w = acc[i][7] + bb[7];
                *(float4*)(C + (size_t)m * 64 + cb) = v0;
                *(float4*)(C + (size_t)m * 64 + cb + 4) = v1;
            }
        }
    }
}

extern "C" void kernel_launch(void* const* d_in, const int* in_sizes, int n_in,
                              void* d_out, int out_size, void* d_ws, size_t ws_size,
                              hipStream_t stream) {
    const float* x    = (const float*)d_in[0];
    const int*   ei   = (const int*)d_in[1];
    const float* W1   = (const float*)d_in[2];
    const float* b1   = (const float*)d_in[3];
    const float* Wmu  = (const float*)d_in[4];
    const float* bmu  = (const float*)d_in[5];
    const float* Wls  = (const float*)d_in[6];
    const float* bls  = (const float*)d_in[7];

    const int N = in_sizes[0] / 256;   // 100000
    const int E = in_sizes[1] / 2;     // 1600000
    const int* src = ei;
    const int* dst = ei + E;

    float* out_mu = (float*)d_out;
    float* out_ls = out_mu + (size_t)N * 64;

    char* wsb = (char*)d_ws;
    const size_t H_BYTES = (size_t)N * 128 * 4;          // 51.2 MB
    const size_t DINV_OFF = 0;
    const size_t BUFA_OFF = 512 * 1024;
    float* dinv = (float*)(wsb + DINV_OFF);
    float* bufA = (float*)(wsb + BUFA_OFF);              // h1, later agg2
    float* bufB;                                          // agg1 -> h
    if (ws_size >= BUFA_OFF + 2 * H_BYTES) {
        bufB = (float*)(wsb + BUFA_OFF + H_BYTES);
    } else {
        bufB = (float*)d_out;  // safe: d_out fully rewritten by final GEMM
    }

    const int nBlkN   = (N + 255) / 256;
    const int nBlkE   = (E + 255) / 256;
    const int nBlkEl  = (N * 32 + 255) / 256;   // float4 elementwise over N*128
    const int nBlkAgg = E / 4 + 1;              // one wave (64 lanes) per edge
    const int nBlkGemm = (N + 127) / 128;

    // 1. degrees + dinv
    k_init_deg<<<nBlkN, 256, 0, stream>>>(dinv, N);
    k_count_deg<<<nBlkE, 256, 0, stream>>>(dst, dinv, E);
    k_rsqrt<<<nBlkN, 256, 0, stream>>>(dinv, N);

    // 2. h1 = x @ W1
    k_gemm<256, 0><<<nBlkGemm, 256, 0, stream>>>(x, W1, nullptr, bufA, nullptr,
                                                 nullptr, nullptr, N);

    // 3. agg1 = A_norm * h1
    k_selfloop<<<nBlkEl, 256, 0, stream>>>(bufA, dinv, bufB, N);
    k_agg_edges<<<nBlkAgg, 256, 0, stream>>>(src, dst, dinv, bufA, bufB, E);

    // 4. h = relu(agg1 + b1)
    k_relu_bias<<<nBlkEl, 256, 0, stream>>>(bufB, b1, N);

    // 5. agg2 = A_norm * h   (into bufA, h1 dead)
    k_selfloop<<<nBlkEl, 256, 0, stream>>>(bufB, dinv, bufA, N);
    k_agg_edges<<<nBlkAgg, 256, 0, stream>>>(src, dst, dinv, bufB, bufA, E);

    // 6. mu / logstd
    k_gemm<128, 1><<<nBlkGemm, 256, 0, stream>>>(bufA, Wmu, Wls, out_mu, out_ls,
                                                 bmu, bls, N);
}

// Round 2
// 582.427 us; speedup vs baseline: 4.9738x; 4.9738x over previous
//
#include <hip/hip_runtime.h>

// ---------------------------------------------------------------------------
// VariationalGCNEncoder: mu/logstd = GCNConv(relu(GCNConv(x)))
// N=100000, E=1600000, IN=256, HID=128, OUT=64
//
// R2: replace per-edge float atomics (205M/pass, 1300us) with a CSR
// gather-reduce built per call:
//   1. histogram cnt[dst]   (int atomics, 1.6M)
//   2. dinv = rsqrt(cnt+1)
//   3. rowptr = exclusive_scan(cnt)     (3-kernel scan)
//   4. scatter (src, dinv[s]*dinv[d]) into CSR buckets (int2 packed)
//   5. h1 = x @ W1                      (f32 GEMM, 8x8 reg tile)
//   6. h  = agg_csr(h1) + bias,relu     (one wave per node, gather-reduce)
//   7. agg2 = agg_csr(h)
//   8. mu|ls = agg2 @ [W_mu|W_ls] + bias (fused GEMM)
// ---------------------------------------------------------------------------

__global__ __launch_bounds__(256) void k_count(const int* __restrict__ dst,
                                               int* __restrict__ cnt, int E) {
    int e = blockIdx.x * 256 + threadIdx.x;
    if (e < E) atomicAdd(&cnt[dst[e]], 1);
}

__global__ __launch_bounds__(256) void k_dinv(const int* __restrict__ cnt,
                                              float* __restrict__ dinv, int N) {
    int i = blockIdx.x * 256 + threadIdx.x;
    if (i < N) dinv[i] = rsqrtf((float)cnt[i] + 1.0f);  // +1 self-loop
}

// ---- 3-kernel exclusive scan over cnt[N] -> rowptr[N+1] --------------------
__global__ __launch_bounds__(256) void k_scan1(const int* __restrict__ cnt,
                                               int* __restrict__ rowptr,
                                               int* __restrict__ bsum, int N) {
    __shared__ int sh[256];
    const int t = threadIdx.x;
    const int base = blockIdx.x * 1024;
    int v[4], s = 0;
#pragma unroll
    for (int i = 0; i < 4; i++) {
        int idx = base + t * 4 + i;
        v[i] = (idx < N) ? cnt[idx] : 0;
        s += v[i];
    }
    sh[t] = s;
    __syncthreads();
    for (int off = 1; off < 256; off <<= 1) {
        int x = (t >= off) ? sh[t - off] : 0;
        __syncthreads();
        sh[t] += x;
        __syncthreads();
    }
    int run = (t > 0) ? sh[t - 1] : 0;
    if (t == 255) bsum[blockIdx.x] = sh[255];
#pragma unroll
    for (int i = 0; i < 4; i++) {
        int idx = base + t * 4 + i;
        if (idx < N) rowptr[idx] = run;
        run += v[i];
    }
}

__global__ __launch_bounds__(256) void k_scan2(int* __restrict__ bsum, int nb) {
    __shared__ int sh[256];
    const int t = threadIdx.x;
    sh[t] = (t < nb) ? bsum[t] : 0;
    __syncthreads();
    for (int off = 1; off < 256; off <<= 1) {
        int x = (t >= off) ? sh[t - off] : 0;
        __syncthreads();
        sh[t] += x;
        __syncthreads();
    }
    if (t < nb) bsum[t] = (t > 0) ? sh[t - 1] : 0;
}

__global__ __launch_bounds__(256) void k_scan3(int* __restrict__ rowptr,
                                               const int* __restrict__ bsum,
                                               int N, int E) {
    int idx = blockIdx.x * 256 + threadIdx.x;
    if (idx < N) rowptr[idx] += bsum[idx >> 10];
    if (idx == 0) rowptr[N] = E;
}

// ---- scatter edges into CSR buckets: cw[p] = (src, weight) -----------------
__global__ __launch_bounds__(256) void k_scatter(const int* __restrict__ src,
                                                 const int* __restrict__ dst,
                                                 const int* __restrict__ rowptr,
                                                 int* __restrict__ cursor,
                                                 const float* __restrict__ dinv,
                                                 int2* __restrict__ cw, int E) {
    int e = blockIdx.x * 256 + threadIdx.x;
    if (e >= E) return;
    int s = src[e], d = dst[e];
    int p = rowptr[d] + atomicAdd(&cursor[d], 1);
    cw[p] = make_int2(s, __float_as_int(dinv[s] * dinv[d]));
}

// ---- CSR gather-reduce: one wave per node, lane = 2 channels ---------------
// EPI==1: out = relu(acc + bias)   (layer-1 epilogue fused)
template <int EPI>
__global__ __launch_bounds__(256) void k_agg_csr(const float* __restrict__ Hin,
                                                 const int* __restrict__ rowptr,
                                                 const int2* __restrict__ cw,
                                                 const float* __restrict__ dinv,
                                                 const float* __restrict__ bias,
                                                 float* __restrict__ Hout, int N) {
    int node = (blockIdx.x * 256 + threadIdx.x) >> 6;
    int lane = threadIdx.x & 63;
    if (node >= N) return;
    float di = dinv[node];
    float w0 = di * di;  // self-loop weight
    float2 acc = ((const float2*)(Hin + (size_t)node * 128))[lane];
    acc.x *= w0;
    acc.y *= w0;
    int e = rowptr[node], end = rowptr[node + 1];
    // 2x unrolled so two gathers are in flight per iteration
    for (; e + 2 <= end; e += 2) {
        int2 c0 = cw[e], c1 = cw[e + 1];
        float2 v0 = ((const float2*)(Hin + (size_t)c0.x * 128))[lane];
        float2 v1 = ((const float2*)(Hin + (size_t)c1.x * 128))[lane];
        float w1 = __int_as_float(c0.y), w2 = __int_as_float(c1.y);
        acc.x = fmaf(w1, v0.x, acc.x);
        acc.y = fmaf(w1, v0.y, acc.y);
        acc.x = fmaf(w2, v1.x, acc.x);
        acc.y = fmaf(w2, v1.y, acc.y);
    }
    if (e < end) {
        int2 c0 = cw[e];
        float2 v0 = ((const float2*)(Hin + (size_t)c0.x * 128))[lane];
        float w1 = __int_as_float(c0.y);
        acc.x = fmaf(w1, v0.x, acc.x);
        acc.y = fmaf(w1, v0.y, acc.y);
    }
    if (EPI == 1) {
        float2 bb = ((const float2*)bias)[lane];
        acc.x = fmaxf(acc.x + bb.x, 0.f);
        acc.y = fmaxf(acc.y + bb.y, 0.f);
    }
    ((float2*)(Hout + (size_t)node * 128))[lane] = acc;
}

// ---------------------------------------------------------------------------
// Tiled f32 GEMM: C[M,128] = A[M,K] @ B[K,128]; 128x128 tile, 8x8 per thread.
// EPI==0: plain store to C0 (stride 128).
// EPI==1: B = [W_mu | W_ls]; cols 0..63 -> C0+bias0, 64..127 -> C1+bias1.
// ---------------------------------------------------------------------------
template <int K, int EPI>
__global__ __launch_bounds__(256) void k_gemm(const float* __restrict__ A,
                                              const float* __restrict__ B0,
                                              const float* __restrict__ B1,
                                              float* __restrict__ C0,
                                              float* __restrict__ C1,
                                              const float* __restrict__ bias0,
                                              const float* __restrict__ bias1, int M) {
    __shared__ float As[32][132];
    __shared__ float Bs[32][128];
    const int t = threadIdx.x;
    const int tx = t & 15, ty = t >> 4;
    const int rowBase = ty * 8, colBase = tx * 8;
    const int blockRow = blockIdx.x * 128;

    float acc[8][8];
#pragma unroll
    for (int i = 0; i < 8; i++)
#pragma unroll
        for (int j = 0; j < 8; j++) acc[i][j] = 0.f;

    for (int k0 = 0; k0 < K; k0 += 32) {
#pragma unroll
        for (int i = 0; i < 4; ++i) {
            int f = i * 256 + t;
            int m = f >> 3;
            int kq = (f & 7) * 4;
            int gr = blockRow + m;
            float4 v = make_float4(0.f, 0.f, 0.f, 0.f);
            if (gr < M) v = *(const float4*)(A + (size_t)gr * K + k0 + kq);
            As[kq + 0][m] = v.x;
            As[kq + 1][m] = v.y;
            As[kq + 2][m] = v.z;
            As[kq + 3][m] = v.w;
        }
#pragma unroll
        for (int i = 0; i < 4; ++i) {
            int f = i * 256 + t;
            int kk = f >> 5;
            int n4 = (f & 31) * 4;
            float4 v;
            if (EPI == 0) {
                v = *(const float4*)(B0 + (size_t)(k0 + kk) * 128 + n4);
            } else {
                const float* Bp = (n4 < 64) ? (B0 + (size_t)(k0 + kk) * 64 + n4)
                                            : (B1 + (size_t)(k0 + kk) * 64 + (n4 - 64));
                v = *(const float4*)Bp;
            }
            *(float4*)&Bs[kk][n4] = v;
        }
        __syncthreads();
#pragma unroll
        for (int k = 0; k < 32; ++k) {
            float a[8], b[8];
            *(float4*)&a[0] = *(const float4*)&As[k][rowBase];
            *(float4*)&a[4] = *(const float4*)&As[k][rowBase + 4];
            *(float4*)&b[0] = *(const float4*)&Bs[k][colBase];
            *(float4*)&b[4] = *(const float4*)&Bs[k][colBase + 4];
#pragma unroll
            for (int i = 0; i < 8; i++)
#pragma unroll
                for (int j = 0; j < 8; j++) acc[i][j] = fmaf(a[i], b[j], acc[i][j]);
        }
        __syncthreads();
    }

    if (EPI == 0) {
#pragma unroll
        for (int i = 0; i < 8; i++) {
            int m = blockRow + rowBase + i;
            if (m < M) {
                *(float4*)(C0 + (size_t)m * 128 + colBase) = *(float4*)&acc[i][0];
                *(float4*)(C0 + (size_t)m * 128 + colBase + 4) = *(float4*)&acc[i][4];
            }
        }
    } else {
        const bool isMu = (colBase < 64);
        const float* bias = isMu ? bias0 : bias1;
        float* C = isMu ? C0 : C1;
        const int cb = isMu ? colBase : colBase - 64;
        float bb[8];
#pragma unroll
        for (int j = 0; j < 8; j++) bb[j] = bias[cb + j];
#pragma unroll
        for (int i = 0; i < 8; i++) {
            int m = blockRow + rowBase + i;
            if (m < M) {
                float4 v0, v1;
                v0.x = acc[i][0] + bb[0]; v0.y = acc[i][1] + bb[1];
                v0.z = acc[i][2] + bb[2]; v0.w = acc[i][3] + bb[3];
                v1.x = acc[i][4] + bb[4]; v1.y = acc[i][5] + bb[5];
                v1.z = acc[i][6] + bb[6]; v1.w = acc[i][7] + bb[7];
                *(float4*)(C + (size_t)m * 64 + cb) = v0;
                *(float4*)(C + (size_t)m * 64 + cb + 4) = v1;
            }
        }
    }
}

extern "C" void kernel_launch(void* const* d_in, const int* in_sizes, int n_in,
                              void* d_out, int out_size, void* d_ws, size_t ws_size,
                              hipStream_t stream) {
    const float* x   = (const float*)d_in[0];
    const int*   ei  = (const int*)d_in[1];
    const float* W1  = (const float*)d_in[2];
    const float* b1  = (const float*)d_in[3];
    const float* Wmu = (const float*)d_in[4];
    const float* bmu = (const float*)d_in[5];
    const float* Wls = (const float*)d_in[6];
    const float* bls = (const float*)d_in[7];

    const int N = in_sizes[0] / 256;  // 100000
    const int E = in_sizes[1] / 2;    // 1600000
    const int* src = ei;
    const int* dst = ei + E;

    float* out_mu = (float*)d_out;
    float* out_ls = out_mu + (size_t)N * 64;

    // ---- workspace layout (MB offsets) ----
    char* wsb = (char*)d_ws;
    const size_t MB = 1024 * 1024;
    const size_t H_BYTES = (size_t)N * 128 * 4;  // 51.2 MB
    int*   cnt    = (int*)(wsb + 0);             // N ints
    int*   rowptr = (int*)(wsb + MB / 2);        // N+1 ints
    int*   cursor = (int*)(wsb + MB);            // N ints
    float* dinv   = (float*)(wsb + 3 * MB / 2);  // N floats
    int*   bsum   = (int*)(wsb + 2 * MB);        // <=256 ints
    int2*  cw     = (int2*)(wsb + 5 * MB / 2);   // E int2 = 12.8 MB
    float* bufA   = (float*)(wsb + 31 * MB / 2); // 15.5 MB: h1 / agg2
    float* bufB;                                 // h
    if (ws_size >= 31 * MB / 2 + 2 * H_BYTES) {
        bufB = (float*)(wsb + 31 * MB / 2 + H_BYTES);
    } else {
        bufB = (float*)d_out;  // safe: d_out fully rewritten by final GEMM
    }

    const int nBlkE    = (E + 255) / 256;
    const int nBlkN    = (N + 255) / 256;
    const int nb1      = (N + 1023) / 1024;       // scan1 blocks (98)
    const int nBlkAgg  = (N + 3) / 4;             // 4 waves/block, 1 wave/node
    const int nBlkGemm = (N + 127) / 128;

    // ---- CSR build ----
    hipMemsetAsync(cnt, 0, (size_t)N * 4, stream);
    hipMemsetAsync(cursor, 0, (size_t)N * 4, stream);
    k_count<<<nBlkE, 256, 0, stream>>>(dst, cnt, E);
    k_dinv<<<nBlkN, 256, 0, stream>>>(cnt, dinv, N);
    k_scan1<<<nb1, 256, 0, stream>>>(cnt, rowptr, bsum, N);
    k_scan2<<<1, 256, 0, stream>>>(bsum, nb1);
    k_scan3<<<(N + 255) / 256, 256, 0, stream>>>(rowptr, bsum, N, E);
    k_scatter<<<nBlkE, 256, 0, stream>>>(src, dst, rowptr, cursor, dinv, cw, E);

    // ---- layer 1 ----
    k_gemm<256, 0><<<nBlkGemm, 256, 0, stream>>>(x, W1, nullptr, bufA, nullptr,
                                                 nullptr, nullptr, N);
    k_agg_csr<1><<<nBlkAgg, 256, 0, stream>>>(bufA, rowptr, cw, dinv, b1, bufB, N);

    // ---- layer 2 ----
    k_agg_csr<0><<<nBlkAgg, 256, 0, stream>>>(bufB, rowptr, cw, dinv, nullptr, bufA, N);
    k_gemm<128, 1><<<nBlkGemm, 256, 0, stream>>>(bufA, Wmu, Wls, out_mu, out_ls,
                                                 bmu, bls, N);
}

// Round 3
// 485.632 us; speedup vs baseline: 5.9651x; 1.1993x over previous
//
#include <hip/hip_runtime.h>

// ---------------------------------------------------------------------------
// VariationalGCNEncoder: mu/logstd = GCNConv(relu(GCNConv(x)))
// N=100000, E=1600000, IN=256, HID=128, OUT=64
//
// R3: (a) GEMMs -> split-bf16 MFMA (x = hi + lo; 3-term hi*hi+hi*lo+lo*hi,
//     residual ~4e-6 rel) with B pre-packed into fragment layout;
//     (b) CSR gather-reduce unrolled 4-deep for MLP.
// ---------------------------------------------------------------------------

typedef unsigned short ushort;
typedef __attribute__((ext_vector_type(8))) short bf16x8;
typedef __attribute__((ext_vector_type(4))) float f32x4;

static __device__ __forceinline__ ushort f2bf(float x) {
    union { float f; unsigned u; } a; a.f = x;
    unsigned r = a.u + 0x7FFFu + ((a.u >> 16) & 1u);   // RNE
    return (ushort)(r >> 16);
}
static __device__ __forceinline__ float bf2f(ushort h) {
    union { unsigned u; float f; } a; a.u = ((unsigned)h) << 16;
    return a.f;
}

// ---------------- CSR build ------------------------------------------------
__global__ __launch_bounds__(256) void k_count(const int* __restrict__ dst,
                                               int* __restrict__ cnt, int E) {
    int e = blockIdx.x * 256 + threadIdx.x;
    if (e < E) atomicAdd(&cnt[dst[e]], 1);
}

__global__ __launch_bounds__(256) void k_dinv(const int* __restrict__ cnt,
                                              float* __restrict__ dinv, int N) {
    int i = blockIdx.x * 256 + threadIdx.x;
    if (i < N) dinv[i] = rsqrtf((float)cnt[i] + 1.0f);
}

__global__ __launch_bounds__(256) void k_scan1(const int* __restrict__ cnt,
                                               int* __restrict__ rowptr,
                                               int* __restrict__ bsum, int N) {
    __shared__ int sh[256];
    const int t = threadIdx.x;
    const int base = blockIdx.x * 1024;
    int v[4], s = 0;
#pragma unroll
    for (int i = 0; i < 4; i++) {
        int idx = base + t * 4 + i;
        v[i] = (idx < N) ? cnt[idx] : 0;
        s += v[i];
    }
    sh[t] = s;
    __syncthreads();
    for (int off = 1; off < 256; off <<= 1) {
        int x = (t >= off) ? sh[t - off] : 0;
        __syncthreads();
        sh[t] += x;
        __syncthreads();
    }
    int run = (t > 0) ? sh[t - 1] : 0;
    if (t == 255) bsum[blockIdx.x] = sh[255];
#pragma unroll
    for (int i = 0; i < 4; i++) {
        int idx = base + t * 4 + i;
        if (idx < N) rowptr[idx] = run;
        run += v[i];
    }
}

__global__ __launch_bounds__(256) void k_scan2(int* __restrict__ bsum, int nb) {
    __shared__ int sh[256];
    const int t = threadIdx.x;
    sh[t] = (t < nb) ? bsum[t] : 0;
    __syncthreads();
    for (int off = 1; off < 256; off <<= 1) {
        int x = (t >= off) ? sh[t - off] : 0;
        __syncthreads();
        sh[t] += x;
        __syncthreads();
    }
    if (t < nb) bsum[t] = (t > 0) ? sh[t - 1] : 0;
}

__global__ __launch_bounds__(256) void k_scan3(int* __restrict__ rowptr,
                                               const int* __restrict__ bsum,
                                               int N, int E) {
    int idx = blockIdx.x * 256 + threadIdx.x;
    if (idx < N) rowptr[idx] += bsum[idx >> 10];
    if (idx == 0) rowptr[N] = E;
}

__global__ __launch_bounds__(256) void k_scatter(const int* __restrict__ src,
                                                 const int* __restrict__ dst,
                                                 const int* __restrict__ rowptr,
                                                 int* __restrict__ cursor,
                                                 const float* __restrict__ dinv,
                                                 int2* __restrict__ cw, int E) {
    int e = blockIdx.x * 256 + threadIdx.x;
    if (e >= E) return;
    int s = src[e], d = dst[e];
    int p = rowptr[d] + atomicAdd(&cursor[d], 1);
    cw[p] = make_int2(s, __float_as_int(dinv[s] * dinv[d]));
}

// ---------------- CSR gather-reduce (1 wave/node, lane = 2 ch) -------------
template <int EPI>
__global__ __launch_bounds__(256) void k_agg_csr(const float* __restrict__ Hin,
                                                 const int* __restrict__ rowptr,
                                                 const int2* __restrict__ cw,
                                                 const float* __restrict__ dinv,
                                                 const float* __restrict__ bias,
                                                 float* __restrict__ Hout, int N) {
    int node = (blockIdx.x * 256 + threadIdx.x) >> 6;
    int lane = threadIdx.x & 63;
    if (node >= N) return;
    float di = dinv[node];
    float w0 = di * di;
    float2 acc = ((const float2*)(Hin + (size_t)node * 128))[lane];
    acc.x *= w0;
    acc.y *= w0;
    int e = rowptr[node], end = rowptr[node + 1];
    for (; e + 4 <= end; e += 4) {
        int2 c0 = cw[e], c1 = cw[e + 1], c2 = cw[e + 2], c3 = cw[e + 3];
        float2 v0 = ((const float2*)(Hin + (size_t)c0.x * 128))[lane];
        float2 v1 = ((const float2*)(Hin + (size_t)c1.x * 128))[lane];
        float2 v2 = ((const float2*)(Hin + (size_t)c2.x * 128))[lane];
        float2 v3 = ((const float2*)(Hin + (size_t)c3.x * 128))[lane];
        float w1 = __int_as_float(c0.y), w2 = __int_as_float(c1.y);
        float w3 = __int_as_float(c2.y), w4 = __int_as_float(c3.y);
        acc.x = fmaf(w1, v0.x, acc.x); acc.y = fmaf(w1, v0.y, acc.y);
        acc.x = fmaf(w2, v1.x, acc.x); acc.y = fmaf(w2, v1.y, acc.y);
        acc.x = fmaf(w3, v2.x, acc.x); acc.y = fmaf(w3, v2.y, acc.y);
        acc.x = fmaf(w4, v3.x, acc.x); acc.y = fmaf(w4, v3.y, acc.y);
    }
    for (; e < end; ++e) {
        int2 c0 = cw[e];
        float2 v0 = ((const float2*)(Hin + (size_t)c0.x * 128))[lane];
        float w1 = __int_as_float(c0.y);
        acc.x = fmaf(w1, v0.x, acc.x);
        acc.y = fmaf(w1, v0.y, acc.y);
    }
    if (EPI == 1) {
        float2 bb = ((const float2*)bias)[lane];
        acc.x = fmaxf(acc.x + bb.x, 0.f);
        acc.y = fmaxf(acc.y + bb.y, 0.f);
    }
    ((float2*)(Hout + (size_t)node * 128))[lane] = acc;
}

// ---------------- B pre-pack into MFMA fragment layout ---------------------
// Output layout: [kgrp = k/8][col 0..127][kin = k%8] ushort, hi and lo.
// B1==nullptr: B0 is [K][128]. Else B = [B0 | B1] with each [K][64].
__global__ __launch_bounds__(256) void k_prep_B(const float* __restrict__ B0,
                                                const float* __restrict__ B1,
                                                ushort* __restrict__ hi,
                                                ushort* __restrict__ lo, int Kgrps) {
    int i = blockIdx.x * 256 + threadIdx.x;
    if (i >= Kgrps * 128) return;
    int kgrp = i >> 7, col = i & 127;
    union { ushort u[8]; uint4 v; } h, l;
#pragma unroll
    for (int j = 0; j < 8; ++j) {
        int k = kgrp * 8 + j;
        float x = (B1 == nullptr)
                      ? B0[(size_t)k * 128 + col]
                      : ((col < 64) ? B0[(size_t)k * 64 + col]
                                    : B1[(size_t)k * 64 + col - 64]);
        h.u[j] = f2bf(x);
        l.u[j] = f2bf(x - bf2f(h.u[j]));
    }
    *(uint4*)(hi + (size_t)i * 8) = h.v;
    *(uint4*)(lo + (size_t)i * 8) = l.v;
}

// ---------------- split-bf16 MFMA GEMM -------------------------------------
// C[M,128] = A[M,K] @ B[K,128], A f32 (split in-register), B pre-packed.
// 128x128 block tile, 4 waves, wave = 32 rows x 128 cols, 16x16x32 MFMA.
// EPI==0: C0 stride 128.  EPI==1: cols 0..63 -> C0+bias0, 64..127 -> C1+bias1.
template <int K, int EPI>
__global__ __launch_bounds__(256) void k_gemm_mfma(
    const float* __restrict__ A, const ushort* __restrict__ Bph,
    const ushort* __restrict__ Bpl, float* __restrict__ C0,
    float* __restrict__ C1, const float* __restrict__ bias0,
    const float* __restrict__ bias1, int M) {
    __shared__ ushort sA[2][4][130][8];  // [hi/lo][kgrp][row(+pad)][kin]
    __shared__ ushort sB[2][4][128][8];
    const int t = threadIdx.x;
    const int lane = t & 63, w = t >> 6;
    const int kgrp = lane >> 4, lrow = lane & 15;
    const int rowBase = w * 32;
    const int blockRow = blockIdx.x * 128;

    f32x4 acc[2][8];
#pragma unroll
    for (int mf = 0; mf < 2; ++mf)
#pragma unroll
        for (int nf = 0; nf < 8; ++nf) acc[mf][nf] = (f32x4)0.f;

    for (int c = 0; c < K / 32; ++c) {
        const int k0 = c * 32;
        // ---- stage A chunk (128 rows x 32 k), f32 -> hi/lo bf16
#pragma unroll
        for (int i = 0; i < 4; ++i) {
            int f = i * 256 + t;
            int row = f >> 3;
            int kq = (f & 7) * 4;  // 0,4,..,28
            int gr = blockRow + row;
            float4 v = make_float4(0.f, 0.f, 0.f, 0.f);
            if (gr < M) v = *(const float4*)(A + (size_t)gr * K + k0 + kq);
            union { ushort u[4]; uint2 q; } h, l;
            h.u[0] = f2bf(v.x); l.u[0] = f2bf(v.x - bf2f(h.u[0]));
            h.u[1] = f2bf(v.y); l.u[1] = f2bf(v.y - bf2f(h.u[1]));
            h.u[2] = f2bf(v.z); l.u[2] = f2bf(v.z - bf2f(h.u[2]));
            h.u[3] = f2bf(v.w); l.u[3] = f2bf(v.w - bf2f(h.u[3]));
            int kg = kq >> 3, kin = kq & 7;  // kin in {0,4}
            *(uint2*)&sA[0][kg][row][kin] = h.q;
            *(uint2*)&sA[1][kg][row][kin] = l.q;
        }
        // ---- stage B chunk: straight 16B copies from pre-packed layout
        {
            const uint4* shh = (const uint4*)(Bph + (size_t)c * 4096);
            const uint4* sll = (const uint4*)(Bpl + (size_t)c * 4096);
            uint4* dh = (uint4*)&sB[0][0][0][0];
            uint4* dl = (uint4*)&sB[1][0][0][0];
            dh[t] = shh[t];
            dh[t + 256] = shh[t + 256];
            dl[t] = sll[t];
            dl[t + 256] = sll[t + 256];
        }
        __syncthreads();
        // ---- MFMA: 2 m-frags x 8 n-frags x 3 pairings
        bf16x8 ah[2], al[2];
#pragma unroll
        for (int mf = 0; mf < 2; ++mf) {
            ah[mf] = *(const bf16x8*)&sA[0][kgrp][rowBase + mf * 16 + lrow][0];
            al[mf] = *(const bf16x8*)&sA[1][kgrp][rowBase + mf * 16 + lrow][0];
        }
#pragma unroll
        for (int nf = 0; nf < 8; ++nf) {
            bf16x8 bh = *(const bf16x8*)&sB[0][kgrp][nf * 16 + lrow][0];
            bf16x8 bl = *(const bf16x8*)&sB[1][kgrp][nf * 16 + lrow][0];
#pragma unroll
            for (int mf = 0; mf < 2; ++mf) {
                acc[mf][nf] = __builtin_amdgcn_mfma_f32_16x16x32_bf16(
                    ah[mf], bh, acc[mf][nf], 0, 0, 0);
                acc[mf][nf] = __builtin_amdgcn_mfma_f32_16x16x32_bf16(
                    ah[mf], bl, acc[mf][nf], 0, 0, 0);
                acc[mf][nf] = __builtin_amdgcn_mfma_f32_16x16x32_bf16(
                    al[mf], bh, acc[mf][nf], 0, 0, 0);
            }
        }
        __syncthreads();
    }

    // ---- epilogue: C/D layout col = lane&15, row = (lane>>4)*4 + reg
    if (EPI == 0) {
#pragma unroll
        for (int mf = 0; mf < 2; ++mf)
#pragma unroll
            for (int reg = 0; reg < 4; ++reg) {
                int row = blockRow + rowBase + mf * 16 + kgrp * 4 + reg;
                if (row < M) {
#pragma unroll
                    for (int nf = 0; nf < 8; ++nf)
                        C0[(size_t)row * 128 + nf * 16 + lrow] = acc[mf][nf][reg];
                }
            }
    } else {
        float bv[8];
#pragma unroll
        for (int nf = 0; nf < 8; ++nf)
            bv[nf] = (nf < 4) ? bias0[nf * 16 + lrow] : bias1[(nf - 4) * 16 + lrow];
#pragma unroll
        for (int mf = 0; mf < 2; ++mf)
#pragma unroll
            for (int reg = 0; reg < 4; ++reg) {
                int row = blockRow + rowBase + mf * 16 + kgrp * 4 + reg;
                if (row < M) {
#pragma unroll
                    for (int nf = 0; nf < 4; ++nf)
                        C0[(size_t)row * 64 + nf * 16 + lrow] = acc[mf][nf][reg] + bv[nf];
#pragma unroll
                    for (int nf = 4; nf < 8; ++nf)
                        C1[(size_t)row * 64 + (nf - 4) * 16 + lrow] =
                            acc[mf][nf][reg] + bv[nf];
                }
            }
    }
}

extern "C" void kernel_launch(void* const* d_in, const int* in_sizes, int n_in,
                              void* d_out, int out_size, void* d_ws, size_t ws_size,
                              hipStream_t stream) {
    const float* x   = (const float*)d_in[0];
    const int*   ei  = (const int*)d_in[1];
    const float* W1  = (const float*)d_in[2];
    const float* b1  = (const float*)d_in[3];
    const float* Wmu = (const float*)d_in[4];
    const float* bmu = (const float*)d_in[5];
    const float* Wls = (const float*)d_in[6];
    const float* bls = (const float*)d_in[7];

    const int N = in_sizes[0] / 256;  // 100000
    const int E = in_sizes[1] / 2;    // 1600000
    const int* src = ei;
    const int* dst = ei + E;

    float* out_mu = (float*)d_out;
    float* out_ls = out_mu + (size_t)N * 64;

    // ---- workspace layout ----
    char* wsb = (char*)d_ws;
    const size_t KB = 1024, MB = 1024 * 1024;
    const size_t H_BYTES = (size_t)N * 128 * 4;  // 51.2 MB
    int*    cnt    = (int*)(wsb + 0);
    int*    rowptr = (int*)(wsb + 512 * KB);
    int*    cursor = (int*)(wsb + 1 * MB);
    float*  dinv   = (float*)(wsb + 1 * MB + 512 * KB);
    int*    bsum   = (int*)(wsb + 2 * MB);
    ushort* Bp1h   = (ushort*)(wsb + 2 * MB + 256 * KB);   // 64 KB
    ushort* Bp1l   = (ushort*)(wsb + 2 * MB + 320 * KB);   // 64 KB
    ushort* Bp2h   = (ushort*)(wsb + 2 * MB + 384 * KB);   // 32 KB
    ushort* Bp2l   = (ushort*)(wsb + 2 * MB + 416 * KB);   // 32 KB
    int2*   cw     = (int2*)(wsb + 2 * MB + 512 * KB);     // 12.8 MB
    float*  bufA   = (float*)(wsb + 15 * MB + 512 * KB);   // h1 / agg2
    float*  bufB;                                          // h
    if (ws_size >= 15 * MB + 512 * KB + 2 * H_BYTES) {
        bufB = (float*)(wsb + 15 * MB + 512 * KB + H_BYTES);
    } else {
        bufB = (float*)d_out;  // safe: d_out fully rewritten by final GEMM
    }

    const int nBlkE    = (E + 255) / 256;
    const int nBlkN    = (N + 255) / 256;
    const int nb1      = (N + 1023) / 1024;
    const int nBlkAgg  = (N + 3) / 4;
    const int nBlkGemm = (N + 127) / 128;

    // ---- CSR build + B pre-pack ----
    hipMemsetAsync(cnt, 0, (size_t)N * 4, stream);
    hipMemsetAsync(cursor, 0, (size_t)N * 4, stream);
    k_prep_B<<<16, 256, 0, stream>>>(W1, nullptr, Bp1h, Bp1l, 32);
    k_prep_B<<<8, 256, 0, stream>>>(Wmu, Wls, Bp2h, Bp2l, 16);
    k_count<<<nBlkE, 256, 0, stream>>>(dst, cnt, E);
    k_dinv<<<nBlkN, 256, 0, stream>>>(cnt, dinv, N);
    k_scan1<<<nb1, 256, 0, stream>>>(cnt, rowptr, bsum, N);
    k_scan2<<<1, 256, 0, stream>>>(bsum, nb1);
    k_scan3<<<(N + 255) / 256, 256, 0, stream>>>(rowptr, bsum, N, E);
    k_scatter<<<nBlkE, 256, 0, stream>>>(src, dst, rowptr, cursor, dinv, cw, E);

    // ---- layer 1 ----
    k_gemm_mfma<256, 0><<<nBlkGemm, 256, 0, stream>>>(
        x, Bp1h, Bp1l, bufA, nullptr, nullptr, nullptr, N);
    k_agg_csr<1><<<nBlkAgg, 256, 0, stream>>>(bufA, rowptr, cw, dinv, b1, bufB, N);

    // ---- layer 2 ----
    k_agg_csr<0><<<nBlkAgg, 256, 0, stream>>>(bufB, rowptr, cw, dinv, nullptr, bufA, N);
    k_gemm_mfma<128, 1><<<nBlkGemm, 256, 0, stream>>>(
        bufA, Bp2h, Bp2l, out_mu, out_ls, bmu, bls, N);
}

// Round 4
// 431.607 us; speedup vs baseline: 6.7118x; 1.1252x over previous
//
#include <hip/hip_runtime.h>
#include <hip/hip_fp16.h>

// ---------------------------------------------------------------------------
// VariationalGCNEncoder: mu/logstd = GCNConv(relu(GCNConv(x)))
// N=100000, E=1600000, IN=256, HID=128, OUT=64
//
// R4: (a) H stored fp16 (halves gather bytes; 2^-12 rel error);
//     (b) rows pre-scaled by dinv => gather is pure adds, scatter stores src only;
//     (c) no-LDS MFMA GEMMs (A direct-to-frag, B tiny & prepacked, no barriers);
//     (d) hidden channels stored in MFMA lane order (j = lrow*8+nf) so the
//         GEMM1 epilogue stores 16B coalesced; b1/B2 pre-permuted to match.
// ---------------------------------------------------------------------------

typedef unsigned short ushort;
typedef __attribute__((ext_vector_type(8))) short bf16x8;
typedef __attribute__((ext_vector_type(8))) _Float16 f16x8;
typedef __attribute__((ext_vector_type(4))) float f32x4;

union U16x8 { uint4 q; ushort u[8]; bf16x8 b; f16x8 h; };

static __device__ __forceinline__ ushort f2bf(float x) {
    union { float f; unsigned u; } a; a.f = x;
    unsigned r = a.u + 0x7FFFu + ((a.u >> 16) & 1u);  // RNE
    return (ushort)(r >> 16);
}
static __device__ __forceinline__ float bf2f(ushort h) {
    union { unsigned u; float f; } a; a.u = ((unsigned)h) << 16;
    return a.f;
}

// ---------------- CSR build ------------------------------------------------
__global__ __launch_bounds__(256) void k_count(const int* __restrict__ dst,
                                               int* __restrict__ cnt, int E) {
    int e = blockIdx.x * 256 + threadIdx.x;
    if (e < E) atomicAdd(&cnt[dst[e]], 1);
}

__global__ __launch_bounds__(256) void k_dinv(const int* __restrict__ cnt,
                                              float* __restrict__ dinv, int N) {
    int i = blockIdx.x * 256 + threadIdx.x;
    if (i < N) dinv[i] = rsqrtf((float)cnt[i] + 1.0f);  // +1 self-loop
}

__global__ __launch_bounds__(256) void k_scan1(const int* __restrict__ cnt,
                                               int* __restrict__ rowptr,
                                               int* __restrict__ bsum, int N) {
    __shared__ int sh[256];
    const int t = threadIdx.x;
    const int base = blockIdx.x * 1024;
    int v[4], s = 0;
#pragma unroll
    for (int i = 0; i < 4; i++) {
        int idx = base + t * 4 + i;
        v[i] = (idx < N) ? cnt[idx] : 0;
        s += v[i];
    }
    sh[t] = s;
    __syncthreads();
    for (int off = 1; off < 256; off <<= 1) {
        int x = (t >= off) ? sh[t - off] : 0;
        __syncthreads();
        sh[t] += x;
        __syncthreads();
    }
    int run = (t > 0) ? sh[t - 1] : 0;
    if (t == 255) bsum[blockIdx.x] = sh[255];
#pragma unroll
    for (int i = 0; i < 4; i++) {
        int idx = base + t * 4 + i;
        if (idx < N) rowptr[idx] = run;
        run += v[i];
    }
}

__global__ __launch_bounds__(256) void k_scan2(int* __restrict__ bsum, int nb) {
    __shared__ int sh[256];
    const int t = threadIdx.x;
    sh[t] = (t < nb) ? bsum[t] : 0;
    __syncthreads();
    for (int off = 1; off < 256; off <<= 1) {
        int x = (t >= off) ? sh[t - off] : 0;
        __syncthreads();
        sh[t] += x;
        __syncthreads();
    }
    if (t < nb) bsum[t] = (t > 0) ? sh[t - 1] : 0;
}

// also fills cursor[] with a second copy of rowptr for the scatter
__global__ __launch_bounds__(256) void k_scan3(int* __restrict__ rowptr,
                                               int* __restrict__ cursor,
                                               const int* __restrict__ bsum,
                                               int N, int E) {
    int idx = blockIdx.x * 256 + threadIdx.x;
    if (idx < N) {
        int v = rowptr[idx] + bsum[idx >> 10];
        rowptr[idx] = v;
        cursor[idx] = v;
    }
    if (idx == 0) rowptr[N] = E;
}

__global__ __launch_bounds__(256) void k_scatter(const int* __restrict__ src,
                                                 const int* __restrict__ dst,
                                                 int* __restrict__ cursor,
                                                 int* __restrict__ cw, int E) {
    int e = blockIdx.x * 256 + threadIdx.x;
    if (e >= E) return;
    int s = src[e], d = dst[e];
    int p = atomicAdd(&cursor[d], 1);
    cw[p] = s;
}

// ---------------- weight pre-pack ------------------------------------------
// GEMM1 B: W1[256][128] -> bf16 hi/lo, layout [kgrp=k/8][col][k%8], logical k.
__global__ __launch_bounds__(256) void k_prep_B1(const float* __restrict__ W,
                                                 ushort* __restrict__ hi,
                                                 ushort* __restrict__ lo) {
    int i = blockIdx.x * 256 + threadIdx.x;  // 32*128 entries
    if (i >= 32 * 128) return;
    int kgrp = i >> 7, col = i & 127;
    U16x8 h, l;
#pragma unroll
    for (int j = 0; j < 8; ++j) {
        float x = W[(size_t)(kgrp * 8 + j) * 128 + col];
        h.u[j] = f2bf(x);
        l.u[j] = f2bf(x - bf2f(h.u[j]));
    }
    *(uint4*)(hi + (size_t)i * 8) = h.q;
    *(uint4*)(lo + (size_t)i * 8) = l.q;
}

// GEMM2 B: [Wmu|Wls][128][64+64] -> f16 hi/lo, K-rows permuted to stored
// hidden order: stored_k = kgrp*8+j  <->  logical_k = j*16 + kgrp.
__global__ __launch_bounds__(256) void k_prep_B2(const float* __restrict__ Wmu,
                                                 const float* __restrict__ Wls,
                                                 ushort* __restrict__ hi,
                                                 ushort* __restrict__ lo) {
    int i = blockIdx.x * 256 + threadIdx.x;  // 16*128 entries
    if (i >= 16 * 128) return;
    int kgrp = i >> 7, col = i & 127;
    U16x8 h, l;
#pragma unroll
    for (int j = 0; j < 8; ++j) {
        int lk = j * 16 + kgrp;  // logical hidden index
        float x = (col < 64) ? Wmu[(size_t)lk * 64 + col]
                             : Wls[(size_t)lk * 64 + col - 64];
        __half hh = __float2half(x);
        float r = x - __half2float(hh);
        __half ll = __float2half(r);
        h.u[j] = __half_as_ushort(hh);
        l.u[j] = __half_as_ushort(ll);
    }
    *(uint4*)(hi + (size_t)i * 8) = h.q;
    *(uint4*)(lo + (size_t)i * 8) = l.q;
}

// b1 permuted to stored order: b1p[j] = b1[(j&7)*16 + (j>>3)]
__global__ __launch_bounds__(128) void k_prep_b1(const float* __restrict__ b1,
                                                 float* __restrict__ b1p) {
    int j = threadIdx.x;
    if (j < 128) b1p[j] = b1[(j & 7) * 16 + (j >> 3)];
}

// ---------------- GEMM1: h1' = dinv * (x @ W1), fp16 stored-order ----------
// No LDS, no barriers. 128x128 block tile, 4 waves, wave = 32 rows.
__global__ __launch_bounds__(256) void k_gemm1(const float* __restrict__ A,
                                               const ushort* __restrict__ Bph,
                                               const ushort* __restrict__ Bpl,
                                               const float* __restrict__ dinv,
                                               __half* __restrict__ H1, int M) {
    const int t = threadIdx.x, lane = t & 63;
    const int kgrp = lane >> 4, lrow = lane & 15;
    const int rowBase = blockIdx.x * 128 + (t >> 6) * 32;

    f32x4 acc[2][8];
#pragma unroll
    for (int mf = 0; mf < 2; ++mf)
#pragma unroll
        for (int nf = 0; nf < 8; ++nf) acc[mf][nf] = (f32x4)0.f;

    for (int c = 0; c < 8; ++c) {  // K=256, 32 per chunk
        bf16x8 ah[2], al[2];
#pragma unroll
        for (int mf = 0; mf < 2; ++mf) {
            int r = rowBase + mf * 16 + lrow;
            if (r >= M) r = M - 1;
            const float* ap = A + (size_t)r * 256 + c * 32 + kgrp * 8;
            float4 x0 = *(const float4*)ap;
            float4 x1 = *(const float4*)(ap + 4);
            float v[8] = {x0.x, x0.y, x0.z, x0.w, x1.x, x1.y, x1.z, x1.w};
            U16x8 h, l;
#pragma unroll
            for (int i = 0; i < 8; ++i) {
                h.u[i] = f2bf(v[i]);
                l.u[i] = f2bf(v[i] - bf2f(h.u[i]));
            }
            ah[mf] = h.b;
            al[mf] = l.b;
        }
#pragma unroll
        for (int nf = 0; nf < 8; ++nf) {
            size_t bo = ((size_t)(c * 4 + kgrp) * 128 + nf * 16 + lrow) * 8;
            U16x8 bh, bl;
            bh.q = *(const uint4*)(Bph + bo);
            bl.q = *(const uint4*)(Bpl + bo);
#pragma unroll
            for (int mf = 0; mf < 2; ++mf) {
                acc[mf][nf] = __builtin_amdgcn_mfma_f32_16x16x32_bf16(
                    ah[mf], bh.b, acc[mf][nf], 0, 0, 0);
                acc[mf][nf] = __builtin_amdgcn_mfma_f32_16x16x32_bf16(
                    ah[mf], bl.b, acc[mf][nf], 0, 0, 0);
                acc[mf][nf] = __builtin_amdgcn_mfma_f32_16x16x32_bf16(
                    al[mf], bh.b, acc[mf][nf], 0, 0, 0);
            }
        }
    }
    // epilogue: row = rowBase + mf*16 + kgrp*4 + reg; store 8 halfs (stored order)
#pragma unroll
    for (int mf = 0; mf < 2; ++mf)
#pragma unroll
        for (int reg = 0; reg < 4; ++reg) {
            int row = rowBase + mf * 16 + kgrp * 4 + reg;
            if (row < M) {
                float dv = dinv[row];
                union { uint4 q; __half h[8]; } o;
#pragma unroll
                for (int nf = 0; nf < 8; ++nf)
                    o.h[nf] = __float2half(acc[mf][nf][reg] * dv);
                *(uint4*)(H1 + (size_t)row * 128 + lrow * 8) = o.q;
            }
        }
}

// ---------------- CSR gather (pure adds; rows pre-scaled) ------------------
// EPI==1: out = dinv * relu(dinv*acc + b1p)   (write next layer's scaled rows)
// EPI==0: out = dinv * acc                    (true agg2, GEMM2 input)
template <int EPI>
__global__ __launch_bounds__(256) void k_agg(const __half* __restrict__ Hin,
                                             const int* __restrict__ rowptr,
                                             const int* __restrict__ cw,
                                             const float* __restrict__ dinv,
                                             const float* __restrict__ b1p,
                                             __half* __restrict__ Hout, int N) {
    int node = (blockIdx.x * 256 + threadIdx.x) >> 6;
    int lane = threadIdx.x & 63;
    if (node >= N) return;
    float2 acc = __half22float2(((const __half2*)(Hin + (size_t)node * 128))[lane]);
    int e = rowptr[node], end = rowptr[node + 1];
    for (; e + 4 <= end; e += 4) {
        int s0 = cw[e], s1 = cw[e + 1], s2 = cw[e + 2], s3 = cw[e + 3];
        float2 f0 = __half22float2(((const __half2*)(Hin + (size_t)s0 * 128))[lane]);
        float2 f1 = __half22float2(((const __half2*)(Hin + (size_t)s1 * 128))[lane]);
        float2 f2_ = __half22float2(((const __half2*)(Hin + (size_t)s2 * 128))[lane]);
        float2 f3_ = __half22float2(((const __half2*)(Hin + (size_t)s3 * 128))[lane]);
        acc.x += f0.x; acc.y += f0.y;
        acc.x += f1.x; acc.y += f1.y;
        acc.x += f2_.x; acc.y += f2_.y;
        acc.x += f3_.x; acc.y += f3_.y;
    }
    for (; e < end; ++e) {
        int s0 = cw[e];
        float2 f0 = __half22float2(((const __half2*)(Hin + (size_t)s0 * 128))[lane]);
        acc.x += f0.x; acc.y += f0.y;
    }
    float dv = dinv[node];
    if (EPI == 1) {
        float2 bb = ((const float2*)b1p)[lane];
        acc.x = fmaxf(fmaf(acc.x, dv, bb.x), 0.f) * dv;
        acc.y = fmaxf(fmaf(acc.y, dv, bb.y), 0.f) * dv;
    } else {
        acc.x *= dv;
        acc.y *= dv;
    }
    ((__half2*)(Hout + (size_t)node * 128))[lane] = __float22half2_rn(acc);
}

// ---------------- GEMM2: [mu|ls] = agg2 @ [Wmu|Wls] + bias -----------------
// A fp16 stored-order; B f16 hi/lo split (2 MFMAs); no LDS, no barriers.
__global__ __launch_bounds__(256) void k_gemm2(const __half* __restrict__ A,
                                               const ushort* __restrict__ Bph,
                                               const ushort* __restrict__ Bpl,
                                               float* __restrict__ Cmu,
                                               float* __restrict__ Cls,
                                               const float* __restrict__ bmu,
                                               const float* __restrict__ bls, int M) {
    const int t = threadIdx.x, lane = t & 63;
    const int kgrp = lane >> 4, lrow = lane & 15;
    const int rowBase = blockIdx.x * 128 + (t >> 6) * 32;

    f32x4 acc[2][8];
#pragma unroll
    for (int mf = 0; mf < 2; ++mf)
#pragma unroll
        for (int nf = 0; nf < 8; ++nf) acc[mf][nf] = (f32x4)0.f;

    for (int c = 0; c < 4; ++c) {  // K=128 stored
        f16x8 a[2];
#pragma unroll
        for (int mf = 0; mf < 2; ++mf) {
            int r = rowBase + mf * 16 + lrow;
            if (r >= M) r = M - 1;
            U16x8 u;
            u.q = *(const uint4*)(A + (size_t)r * 128 + c * 32 + kgrp * 8);
            a[mf] = u.h;
        }
#pragma unroll
        for (int nf = 0; nf < 8; ++nf) {
            size_t bo = ((size_t)(c * 4 + kgrp) * 128 + nf * 16 + lrow) * 8;
            U16x8 bh, bl;
            bh.q = *(const uint4*)(Bph + bo);
            bl.q = *(const uint4*)(Bpl + bo);
#pragma unroll
            for (int mf = 0; mf < 2; ++mf) {
                acc[mf][nf] = __builtin_amdgcn_mfma_f32_16x16x32_f16(
                    a[mf], bh.h, acc[mf][nf], 0, 0, 0);
                acc[mf][nf] = __builtin_amdgcn_mfma_f32_16x16x32_f16(
                    a[mf], bl.h, acc[mf][nf], 0, 0, 0);
            }
        }
    }
    float bv[8];
#pragma unroll
    for (int nf = 0; nf < 8; ++nf)
        bv[nf] = (nf < 4) ? bmu[nf * 16 + lrow] : bls[(nf - 4) * 16 + lrow];
#pragma unroll
    for (int mf = 0; mf < 2; ++mf)
#pragma unroll
        for (int reg = 0; reg < 4; ++reg) {
            int row = rowBase + mf * 16 + kgrp * 4 + reg;
            if (row < M) {
#pragma unroll
                for (int nf = 0; nf < 4; ++nf)
                    Cmu[(size_t)row * 64 + nf * 16 + lrow] = acc[mf][nf][reg] + bv[nf];
#pragma unroll
                for (int nf = 4; nf < 8; ++nf)
                    Cls[(size_t)row * 64 + (nf - 4) * 16 + lrow] =
                        acc[mf][nf][reg] + bv[nf];
            }
        }
}

extern "C" void kernel_launch(void* const* d_in, const int* in_sizes, int n_in,
                              void* d_out, int out_size, void* d_ws, size_t ws_size,
                              hipStream_t stream) {
    const float* x   = (const float*)d_in[0];
    const int*   ei  = (const int*)d_in[1];
    const float* W1  = (const float*)d_in[2];
    const float* b1  = (const float*)d_in[3];
    const float* Wmu = (const float*)d_in[4];
    const float* bmu = (const float*)d_in[5];
    const float* Wls = (const float*)d_in[6];
    const float* bls = (const float*)d_in[7];

    const int N = in_sizes[0] / 256;  // 100000
    const int E = in_sizes[1] / 2;    // 1600000
    const int* src = ei;
    const int* dst = ei + E;

    float* out_mu = (float*)d_out;
    float* out_ls = out_mu + (size_t)N * 64;

    // ---- workspace layout ----
    char* wsb = (char*)d_ws;
    const size_t KB = 1024, MB = 1024 * 1024;
    const size_t Hh_BYTES = (size_t)N * 128 * 2;  // 25.6 MB (fp16)
    int*    cnt    = (int*)(wsb + 0);
    int*    rowptr = (int*)(wsb + 512 * KB);
    int*    cursor = (int*)(wsb + 1 * MB);
    float*  dinv   = (float*)(wsb + 1 * MB + 512 * KB);
    int*    bsum   = (int*)(wsb + 2 * MB);             // 1 KB
    float*  b1p    = (float*)(wsb + 2 * MB + 4 * KB);  // 512 B
    ushort* Bp1h   = (ushort*)(wsb + 2 * MB + 64 * KB);
    ushort* Bp1l   = (ushort*)(wsb + 2 * MB + 128 * KB);
    ushort* Bp2h   = (ushort*)(wsb + 2 * MB + 192 * KB);
    ushort* Bp2l   = (ushort*)(wsb + 2 * MB + 224 * KB);
    int*    cw     = (int*)(wsb + 2 * MB + 256 * KB);  // 6.4 MB
    __half* h1     = (__half*)(wsb + 9 * MB);          // 25.6 MB
    __half* hbuf;                                      // h'
    __half* agg2   = (__half*)(wsb + 61 * MB);         // 25.6 MB
    if (ws_size >= 61 * MB + Hh_BYTES) {
        hbuf = (__half*)(wsb + 35 * MB);
    } else {
        hbuf = (__half*)d_out;  // 25.6 <= 51.2 MB; d_out rewritten by GEMM2
        agg2 = (__half*)(wsb + 35 * MB);
    }

    const int nBlkE    = (E + 255) / 256;
    const int nBlkN    = (N + 255) / 256;
    const int nb1      = (N + 1023) / 1024;
    const int nBlkAgg  = (N + 3) / 4;
    const int nBlkGemm = (N + 127) / 128;

    // ---- CSR build + prepacks ----
    hipMemsetAsync(cnt, 0, (size_t)N * 4, stream);
    k_count<<<nBlkE, 256, 0, stream>>>(dst, cnt, E);
    k_dinv<<<nBlkN, 256, 0, stream>>>(cnt, dinv, N);
    k_scan1<<<nb1, 256, 0, stream>>>(cnt, rowptr, bsum, N);
    k_scan2<<<1, 256, 0, stream>>>(bsum, nb1);
    k_scan3<<<(N + 255) / 256, 256, 0, stream>>>(rowptr, cursor, bsum, N, E);
    k_scatter<<<nBlkE, 256, 0, stream>>>(src, dst, cursor, cw, E);
    k_prep_B1<<<16, 256, 0, stream>>>(W1, Bp1h, Bp1l);
    k_prep_B2<<<8, 256, 0, stream>>>(Wmu, Wls, Bp2h, Bp2l);
    k_prep_b1<<<1, 128, 0, stream>>>(b1, b1p);

    // ---- layer 1 ----
    k_gemm1<<<nBlkGemm, 256, 0, stream>>>(x, Bp1h, Bp1l, dinv, h1, N);
    k_agg<1><<<nBlkAgg, 256, 0, stream>>>(h1, rowptr, cw, dinv, b1p, hbuf, N);

    // ---- layer 2 ----
    k_agg<0><<<nBlkAgg, 256, 0, stream>>>(hbuf, rowptr, cw, dinv, nullptr, agg2, N);
    k_gemm2<<<nBlkGemm, 256, 0, stream>>>(agg2, Bp2h, Bp2l, out_mu, out_ls,
                                          bmu, bls, N);
}

// Round 5
// 262.160 us; speedup vs baseline: 11.0500x; 1.6463x over previous
//
#include <hip/hip_runtime.h>
#include <hip/hip_fp16.h>

// ---------------------------------------------------------------------------
// VariationalGCNEncoder: mu/logstd = GCNConv(relu(GCNConv(x)))
// N=100000, E=1600000, IN=256, HID=128, OUT=64
//
// R5: CSR build rewritten as a two-level bucketed counting sort
//     (bucket = dst>>8). All global writes coalesced runs or XCD-local
//     contiguous regions -- kills R4's 105MB partial-line writeback storm
//     (k_scatter 133us). Also: gather unrolled 8-deep.
// Pipeline: bhist -> bscan -> bpart -> bfin(rowptr,dinv,cw)
//           -> gemm1(MFMA split-bf16, fp16 out, prescaled) -> agg -> agg
//           -> gemm2(MFMA f16 hi/lo)
// ---------------------------------------------------------------------------

typedef unsigned short ushort;
typedef __attribute__((ext_vector_type(8))) short bf16x8;
typedef __attribute__((ext_vector_type(8))) _Float16 f16x8;
typedef __attribute__((ext_vector_type(4))) float f32x4;

union U16x8 { uint4 q; ushort u[8]; bf16x8 b; f16x8 h; };

static __device__ __forceinline__ ushort f2bf(float x) {
    union { float f; unsigned u; } a; a.f = x;
    unsigned r = a.u + 0x7FFFu + ((a.u >> 16) & 1u);  // RNE
    return (ushort)(r >> 16);
}
static __device__ __forceinline__ float bf2f(ushort h) {
    union { unsigned u; float f; } a; a.u = ((unsigned)h) << 16;
    return a.f;
}

#define NBUCK 391          // ceil(100000/256)
#define PCHUNK 4096

// ---------------- bucket histogram -----------------------------------------
__global__ __launch_bounds__(256) void k_bhist(const int* __restrict__ dst,
                                               int* __restrict__ bucketCnt, int E) {
    __shared__ int hist[NBUCK];
    const int t = threadIdx.x;
    const int base = blockIdx.x * PCHUNK;
    const int cnt = min(PCHUNK, E - base);
    for (int i = t; i < NBUCK; i += 256) hist[i] = 0;
    __syncthreads();
    for (int i = t; i < cnt; i += 256) atomicAdd(&hist[dst[base + i] >> 8], 1);
    __syncthreads();
    for (int i = t; i < NBUCK; i += 256)
        if (hist[i]) atomicAdd(&bucketCnt[i], hist[i]);
}

// ---------------- bucket scan (1 block, 512 thr) ---------------------------
__global__ __launch_bounds__(512) void k_bscan(const int* __restrict__ bucketCnt,
                                               int* __restrict__ bucketBase,
                                               int* __restrict__ bucketCursor) {
    __shared__ int sc[512];
    const int t = threadIdx.x;
    sc[t] = (t < NBUCK) ? bucketCnt[t] : 0;
    __syncthreads();
    for (int off = 1; off < 512; off <<= 1) {
        int a = (t >= off) ? sc[t - off] : 0;
        __syncthreads();
        sc[t] += a;
        __syncthreads();
    }
    if (t <= NBUCK) {
        int base = (t == 0) ? 0 : sc[t - 1];
        bucketBase[t] = base;
        if (t < NBUCK) bucketCursor[t] = base;
    }
}

// ---------------- partition: LDS counting sort per 4096-edge chunk ---------
__global__ __launch_bounds__(256) void k_bpart(const int* __restrict__ src,
                                               const int* __restrict__ dst,
                                               int* __restrict__ bucketCursor,
                                               unsigned* __restrict__ cwTmp, int E) {
    __shared__ unsigned words[PCHUNK];
    __shared__ ushort buck[PCHUNK];
    __shared__ unsigned sortedW[PCHUNK];
    __shared__ ushort buck2[PCHUNK];
    __shared__ int sc[512];
    __shared__ int rk[NBUCK];
    __shared__ int runBase[NBUCK];
    const int t = threadIdx.x;
    const int base = blockIdx.x * PCHUNK;
    const int cnt = min(PCHUNK, E - base);

    sc[t] = 0; sc[t + 256] = 0;
    for (int i = t; i < NBUCK; i += 256) rk[i] = 0;
    __syncthreads();
    // load + histogram
    for (int i = t; i < cnt; i += 256) {
        int s = src[base + i], d = dst[base + i];
        words[i] = ((unsigned)s << 8) | (unsigned)(d & 255);
        int b = d >> 8;
        buck[i] = (ushort)b;
        atomicAdd(&sc[b], 1);
    }
    __syncthreads();
    // inclusive scan over 512 slots (256 threads, 2 slots each)
    for (int off = 1; off < 512; off <<= 1) {
        int a0 = (t >= off) ? sc[t - off] : 0;
        int a1 = (t + 256 >= off) ? sc[t + 256 - off] : 0;
        __syncthreads();
        sc[t] += a0;
        sc[t + 256] += a1;
        __syncthreads();
    }
    // scatter into bucket-sorted LDS order
    for (int i = t; i < cnt; i += 256) {
        int b = buck[i];
        int excl = b ? sc[b - 1] : 0;
        int p = excl + atomicAdd(&rk[b], 1);
        sortedW[p] = words[i];
        buck2[p] = (ushort)b;
    }
    __syncthreads();
    // reserve global runs (one atomic per non-empty bucket)
    for (int b = t; b < NBUCK; b += 256) {
        int len = rk[b];
        if (len > 0) runBase[b] = atomicAdd(&bucketCursor[b], len);
    }
    __syncthreads();
    // coalesced write-out of sorted runs
    for (int i = t; i < cnt; i += 256) {
        int b = buck2[i];
        int excl = b ? sc[b - 1] : 0;
        cwTmp[runBase[b] + (i - excl)] = sortedW[i];
    }
}

// ---------------- finalize: per-bucket node sort -> rowptr, dinv, cw -------
__global__ __launch_bounds__(256) void k_bfin(const unsigned* __restrict__ cwTmp,
                                              const int* __restrict__ bucketBase,
                                              int* __restrict__ cw,
                                              int* __restrict__ rowptr,
                                              float* __restrict__ dinv,
                                              int N, int E) {
    __shared__ int hist[256], sc2[256], rk[256];
    const int b = blockIdx.x, t = threadIdx.x;
    const int gbase = bucketBase[b], gend = bucketBase[b + 1];
    const int n0 = b << 8;
    const int nNodes = min(256, N - n0);
    hist[t] = 0;
    rk[t] = 0;
    __syncthreads();
    for (int i = gbase + t; i < gend; i += 256)
        atomicAdd(&hist[cwTmp[i] & 255u], 1);
    __syncthreads();
    sc2[t] = hist[t];
    __syncthreads();
    for (int off = 1; off < 256; off <<= 1) {
        int a = (t >= off) ? sc2[t - off] : 0;
        __syncthreads();
        sc2[t] += a;
        __syncthreads();
    }
    int ex = sc2[t] - hist[t];  // exclusive scan
    if (t < nNodes) {
        rowptr[n0 + t] = gbase + ex;
        dinv[n0 + t] = rsqrtf((float)hist[t] + 1.0f);  // +1 self-loop
    }
    if (b == 0 && t == 0) rowptr[N] = E;
    __syncthreads();
    for (int i = gbase + t; i < gend; i += 256) {
        unsigned w = cwTmp[i];
        int dL = w & 255u;
        int r = atomicAdd(&rk[dL], 1);
        cw[gbase + (sc2[dL] - hist[dL]) + r] = (int)(w >> 8);
    }
}

// ---------------- weight pre-pack ------------------------------------------
__global__ __launch_bounds__(256) void k_prep_B1(const float* __restrict__ W,
                                                 ushort* __restrict__ hi,
                                                 ushort* __restrict__ lo) {
    int i = blockIdx.x * 256 + threadIdx.x;  // 32*128
    if (i >= 32 * 128) return;
    int kgrp = i >> 7, col = i & 127;
    U16x8 h, l;
#pragma unroll
    for (int j = 0; j < 8; ++j) {
        float x = W[(size_t)(kgrp * 8 + j) * 128 + col];
        h.u[j] = f2bf(x);
        l.u[j] = f2bf(x - bf2f(h.u[j]));
    }
    *(uint4*)(hi + (size_t)i * 8) = h.q;
    *(uint4*)(lo + (size_t)i * 8) = l.q;
}

__global__ __launch_bounds__(256) void k_prep_B2(const float* __restrict__ Wmu,
                                                 const float* __restrict__ Wls,
                                                 ushort* __restrict__ hi,
                                                 ushort* __restrict__ lo) {
    int i = blockIdx.x * 256 + threadIdx.x;  // 16*128
    if (i >= 16 * 128) return;
    int kgrp = i >> 7, col = i & 127;
    U16x8 h, l;
#pragma unroll
    for (int j = 0; j < 8; ++j) {
        int lk = j * 16 + kgrp;  // stored_k -> logical hidden index
        float x = (col < 64) ? Wmu[(size_t)lk * 64 + col]
                             : Wls[(size_t)lk * 64 + col - 64];
        __half hh = __float2half(x);
        __half ll = __float2half(x - __half2float(hh));
        h.u[j] = __half_as_ushort(hh);
        l.u[j] = __half_as_ushort(ll);
    }
    *(uint4*)(hi + (size_t)i * 8) = h.q;
    *(uint4*)(lo + (size_t)i * 8) = l.q;
}

__global__ __launch_bounds__(128) void k_prep_b1(const float* __restrict__ b1,
                                                 float* __restrict__ b1p) {
    int j = threadIdx.x;
    if (j < 128) b1p[j] = b1[(j & 7) * 16 + (j >> 3)];
}

// ---------------- GEMM1: h1' = dinv * (x @ W1), fp16 stored-order ----------
__global__ __launch_bounds__(256) void k_gemm1(const float* __restrict__ A,
                                               const ushort* __restrict__ Bph,
                                               const ushort* __restrict__ Bpl,
                                               const float* __restrict__ dinv,
                                               __half* __restrict__ H1, int M) {
    const int t = threadIdx.x, lane = t & 63;
    const int kgrp = lane >> 4, lrow = lane & 15;
    const int rowBase = blockIdx.x * 128 + (t >> 6) * 32;

    f32x4 acc[2][8];
#pragma unroll
    for (int mf = 0; mf < 2; ++mf)
#pragma unroll
        for (int nf = 0; nf < 8; ++nf) acc[mf][nf] = (f32x4)0.f;

    for (int c = 0; c < 8; ++c) {  // K=256
        bf16x8 ah[2], al[2];
#pragma unroll
        for (int mf = 0; mf < 2; ++mf) {
            int r = rowBase + mf * 16 + lrow;
            if (r >= M) r = M - 1;
            const float* ap = A + (size_t)r * 256 + c * 32 + kgrp * 8;
            float4 x0 = *(const float4*)ap;
            float4 x1 = *(const float4*)(ap + 4);
            float v[8] = {x0.x, x0.y, x0.z, x0.w, x1.x, x1.y, x1.z, x1.w};
            U16x8 h, l;
#pragma unroll
            for (int i = 0; i < 8; ++i) {
                h.u[i] = f2bf(v[i]);
                l.u[i] = f2bf(v[i] - bf2f(h.u[i]));
            }
            ah[mf] = h.b;
            al[mf] = l.b;
        }
#pragma unroll
        for (int nf = 0; nf < 8; ++nf) {
            size_t bo = ((size_t)(c * 4 + kgrp) * 128 + nf * 16 + lrow) * 8;
            U16x8 bh, bl;
            bh.q = *(const uint4*)(Bph + bo);
            bl.q = *(const uint4*)(Bpl + bo);
#pragma unroll
            for (int mf = 0; mf < 2; ++mf) {
                acc[mf][nf] = __builtin_amdgcn_mfma_f32_16x16x32_bf16(
                    ah[mf], bh.b, acc[mf][nf], 0, 0, 0);
                acc[mf][nf] = __builtin_amdgcn_mfma_f32_16x16x32_bf16(
                    ah[mf], bl.b, acc[mf][nf], 0, 0, 0);
                acc[mf][nf] = __builtin_amdgcn_mfma_f32_16x16x32_bf16(
                    al[mf], bh.b, acc[mf][nf], 0, 0, 0);
            }
        }
    }
#pragma unroll
    for (int mf = 0; mf < 2; ++mf)
#pragma unroll
        for (int reg = 0; reg < 4; ++reg) {
            int row = rowBase + mf * 16 + kgrp * 4 + reg;
            if (row < M) {
                float dv = dinv[row];
                union { uint4 q; __half h[8]; } o;
#pragma unroll
                for (int nf = 0; nf < 8; ++nf)
                    o.h[nf] = __float2half(acc[mf][nf][reg] * dv);
                *(uint4*)(H1 + (size_t)row * 128 + lrow * 8) = o.q;
            }
        }
}

// ---------------- CSR gather (pure adds; rows pre-scaled) ------------------
template <int EPI>
__global__ __launch_bounds__(256) void k_agg(const __half* __restrict__ Hin,
                                             const int* __restrict__ rowptr,
                                             const int* __restrict__ cw,
                                             const float* __restrict__ dinv,
                                             const float* __restrict__ b1p,
                                             __half* __restrict__ Hout, int N) {
    int node = (blockIdx.x * 256 + threadIdx.x) >> 6;
    int lane = threadIdx.x & 63;
    if (node >= N) return;
    float2 acc = __half22float2(((const __half2*)(Hin + (size_t)node * 128))[lane]);
    int e = rowptr[node], end = rowptr[node + 1];
    for (; e + 8 <= end; e += 8) {
        int s0 = cw[e], s1 = cw[e + 1], s2 = cw[e + 2], s3 = cw[e + 3];
        int s4 = cw[e + 4], s5 = cw[e + 5], s6 = cw[e + 6], s7 = cw[e + 7];
        float2 f0 = __half22float2(((const __half2*)(Hin + (size_t)s0 * 128))[lane]);
        float2 f1 = __half22float2(((const __half2*)(Hin + (size_t)s1 * 128))[lane]);
        float2 f2 = __half22float2(((const __half2*)(Hin + (size_t)s2 * 128))[lane]);
        float2 f3 = __half22float2(((const __half2*)(Hin + (size_t)s3 * 128))[lane]);
        float2 f4 = __half22float2(((const __half2*)(Hin + (size_t)s4 * 128))[lane]);
        float2 f5 = __half22float2(((const __half2*)(Hin + (size_t)s5 * 128))[lane]);
        float2 f6 = __half22float2(((const __half2*)(Hin + (size_t)s6 * 128))[lane]);
        float2 f7 = __half22float2(((const __half2*)(Hin + (size_t)s7 * 128))[lane]);
        acc.x += f0.x; acc.y += f0.y; acc.x += f1.x; acc.y += f1.y;
        acc.x += f2.x; acc.y += f2.y; acc.x += f3.x; acc.y += f3.y;
        acc.x += f4.x; acc.y += f4.y; acc.x += f5.x; acc.y += f5.y;
        acc.x += f6.x; acc.y += f6.y; acc.x += f7.x; acc.y += f7.y;
    }
    for (; e + 2 <= end; e += 2) {
        int s0 = cw[e], s1 = cw[e + 1];
        float2 f0 = __half22float2(((const __half2*)(Hin + (size_t)s0 * 128))[lane]);
        float2 f1 = __half22float2(((const __half2*)(Hin + (size_t)s1 * 128))[lane]);
        acc.x += f0.x; acc.y += f0.y; acc.x += f1.x; acc.y += f1.y;
    }
    if (e < end) {
        int s0 = cw[e];
        float2 f0 = __half22float2(((const __half2*)(Hin + (size_t)s0 * 128))[lane]);
        acc.x += f0.x; acc.y += f0.y;
    }
    float dv = dinv[node];
    if (EPI == 1) {
        float2 bb = ((const float2*)b1p)[lane];
        acc.x = fmaxf(fmaf(acc.x, dv, bb.x), 0.f) * dv;
        acc.y = fmaxf(fmaf(acc.y, dv, bb.y), 0.f) * dv;
    } else {
        acc.x *= dv;
        acc.y *= dv;
    }
    ((__half2*)(Hout + (size_t)node * 128))[lane] = __float22half2_rn(acc);
}

// ---------------- GEMM2: [mu|ls] = agg2 @ [Wmu|Wls] + bias -----------------
__global__ __launch_bounds__(256) void k_gemm2(const __half* __restrict__ A,
                                               const ushort* __restrict__ Bph,
                                               const ushort* __restrict__ Bpl,
                                               float* __restrict__ Cmu,
                                               float* __restrict__ Cls,
                                               const float* __restrict__ bmu,
                                               const float* __restrict__ bls, int M) {
    const int t = threadIdx.x, lane = t & 63;
    const int kgrp = lane >> 4, lrow = lane & 15;
    const int rowBase = blockIdx.x * 128 + (t >> 6) * 32;

    f32x4 acc[2][8];
#pragma unroll
    for (int mf = 0; mf < 2; ++mf)
#pragma unroll
        for (int nf = 0; nf < 8; ++nf) acc[mf][nf] = (f32x4)0.f;

    for (int c = 0; c < 4; ++c) {  // K=128 stored
        f16x8 a[2];
#pragma unroll
        for (int mf = 0; mf < 2; ++mf) {
            int r = rowBase + mf * 16 + lrow;
            if (r >= M) r = M - 1;
            U16x8 u;
            u.q = *(const uint4*)(A + (size_t)r * 128 + c * 32 + kgrp * 8);
            a[mf] = u.h;
        }
#pragma unroll
        for (int nf = 0; nf < 8; ++nf) {
            size_t bo = ((size_t)(c * 4 + kgrp) * 128 + nf * 16 + lrow) * 8;
            U16x8 bh, bl;
            bh.q = *(const uint4*)(Bph + bo);
            bl.q = *(const uint4*)(Bpl + bo);
#pragma unroll
            for (int mf = 0; mf < 2; ++mf) {
                acc[mf][nf] = __builtin_amdgcn_mfma_f32_16x16x32_f16(
                    a[mf], bh.h, acc[mf][nf], 0, 0, 0);
                acc[mf][nf] = __builtin_amdgcn_mfma_f32_16x16x32_f16(
                    a[mf], bl.h, acc[mf][nf], 0, 0, 0);
            }
        }
    }
    float bv[8];
#pragma unroll
    for (int nf = 0; nf < 8; ++nf)
        bv[nf] = (nf < 4) ? bmu[nf * 16 + lrow] : bls[(nf - 4) * 16 + lrow];
#pragma unroll
    for (int mf = 0; mf < 2; ++mf)
#pragma unroll
        for (int reg = 0; reg < 4; ++reg) {
            int row = rowBase + mf * 16 + kgrp * 4 + reg;
            if (row < M) {
#pragma unroll
                for (int nf = 0; nf < 4; ++nf)
                    Cmu[(size_t)row * 64 + nf * 16 + lrow] = acc[mf][nf][reg] + bv[nf];
#pragma unroll
                for (int nf = 4; nf < 8; ++nf)
                    Cls[(size_t)row * 64 + (nf - 4) * 16 + lrow] =
                        acc[mf][nf][reg] + bv[nf];
            }
        }
}

extern "C" void kernel_launch(void* const* d_in, const int* in_sizes, int n_in,
                              void* d_out, int out_size, void* d_ws, size_t ws_size,
                              hipStream_t stream) {
    const float* x   = (const float*)d_in[0];
    const int*   ei  = (const int*)d_in[1];
    const float* W1  = (const float*)d_in[2];
    const float* b1  = (const float*)d_in[3];
    const float* Wmu = (const float*)d_in[4];
    const float* bmu = (const float*)d_in[5];
    const float* Wls = (const float*)d_in[6];
    const float* bls = (const float*)d_in[7];

    const int N = in_sizes[0] / 256;  // 100000
    const int E = in_sizes[1] / 2;    // 1600000
    const int* src = ei;
    const int* dst = ei + E;

    float* out_mu = (float*)d_out;
    float* out_ls = out_mu + (size_t)N * 64;

    // ---- workspace layout ----
    char* wsb = (char*)d_ws;
    const size_t KB = 1024, MB = 1024 * 1024;
    const size_t Hh_BYTES = (size_t)N * 128 * 2;  // 25.6 MB
    int*      bucketCnt    = (int*)(wsb + 0);            // 392 ints
    int*      bucketBase   = (int*)(wsb + 4 * KB);       // 392 ints
    int*      bucketCursor = (int*)(wsb + 8 * KB);       // 392 ints
    float*    b1p          = (float*)(wsb + 16 * KB);    // 512 B
    ushort*   Bp1h         = (ushort*)(wsb + 32 * KB);   // 64 KB
    ushort*   Bp1l         = (ushort*)(wsb + 96 * KB);   // 64 KB
    ushort*   Bp2h         = (ushort*)(wsb + 160 * KB);  // 32 KB
    ushort*   Bp2l         = (ushort*)(wsb + 192 * KB);  // 32 KB
    int*      rowptr       = (int*)(wsb + 256 * KB);     // 400 KB
    float*    dinv         = (float*)(wsb + 768 * KB);   // 400 KB
    unsigned* cwTmp        = (unsigned*)(wsb + 1280 * KB);  // 6.4 MB
    int*      cw           = (int*)(wsb + 8 * MB);          // 6.4 MB
    __half*   h1           = (__half*)(wsb + 15 * MB);      // 25.6 MB
    __half*   hbuf;                                         // h'
    __half*   agg2;
    if (ws_size >= 67 * MB + Hh_BYTES) {
        hbuf = (__half*)(wsb + 41 * MB);
        agg2 = (__half*)(wsb + 67 * MB);
    } else {
        hbuf = (__half*)d_out;  // 25.6 <= 51.2 MB; d_out rewritten by GEMM2
        agg2 = (__half*)(wsb + 41 * MB);
    }

    const int nChunks  = (E + PCHUNK - 1) / PCHUNK;  // 391
    const int nBlkAgg  = (N + 3) / 4;
    const int nBlkGemm = (N + 127) / 128;

    // ---- CSR build (bucketed counting sort) ----
    hipMemsetAsync(bucketCnt, 0, 392 * 4, stream);
    k_bhist<<<nChunks, 256, 0, stream>>>(dst, bucketCnt, E);
    k_bscan<<<1, 512, 0, stream>>>(bucketCnt, bucketBase, bucketCursor);
    k_bpart<<<nChunks, 256, 0, stream>>>(src, dst, bucketCursor, cwTmp, E);
    k_bfin<<<NBUCK, 256, 0, stream>>>(cwTmp, bucketBase, cw, rowptr, dinv, N, E);

    // ---- weight prepacks ----
    k_prep_B1<<<16, 256, 0, stream>>>(W1, Bp1h, Bp1l);
    k_prep_B2<<<8, 256, 0, stream>>>(Wmu, Wls, Bp2h, Bp2l);
    k_prep_b1<<<1, 128, 0, stream>>>(b1, b1p);

    // ---- layer 1 ----
    k_gemm1<<<nBlkGemm, 256, 0, stream>>>(x, Bp1h, Bp1l, dinv, h1, N);
    k_agg<1><<<nBlkAgg, 256, 0, stream>>>(h1, rowptr, cw, dinv, b1p, hbuf, N);

    // ---- layer 2 ----
    k_agg<0><<<nBlkAgg, 256, 0, stream>>>(hbuf, rowptr, cw, dinv, nullptr, agg2, N);
    k_gemm2<<<nBlkGemm, 256, 0, stream>>>(agg2, Bp2h, Bp2l, out_mu, out_ls,
                                          bmu, bls, N);
}